// Round 13
// baseline (927.782 us; speedup 1.0000x reference)
//
#include <hip/hip_runtime.h>
#include <hip/hip_bf16.h>

#define NH 80
#define NKV 8
#define HD 128
#define GROUPS 10
#define SEQ 1024
#define BATCH 2
#define DMODEL 5120
#define NQKV 12288   // 10240 q + 1024 k + 1024 v
#define MROWS 2048   // B*S
#define QCOLS 10240
#define KOFF 10240
#define VOFF 11264
#define ATTN_SCALE 0.08838834764831845f  // 128^-0.5

typedef __attribute__((ext_vector_type(8))) __bf16 bf16x8;
typedef __attribute__((ext_vector_type(4))) float f32x4;

__device__ inline unsigned short f2bf(float f) {
  unsigned u = __float_as_uint(f);
  u = (u + 0x7fffu + ((u >> 16) & 1u)) >> 16;
  return (unsigned short)u;
}
__device__ inline float bf2f(unsigned short h) {
  return __uint_as_float(((unsigned)h) << 16);
}

template <typename T>
__device__ inline T ld_vec(const void* p) {
  T v;
  __builtin_memcpy(&v, p, sizeof(T));
  return v;
}

__device__ inline void gload_lds16(const void* g, void* l) {
  __builtin_amdgcn_global_load_lds(
      (const __attribute__((address_space(1))) void*)g,
      (__attribute__((address_space(3))) void*)l, 16, 0, 0);
}

// ---------------- fused fp32 -> bf16 conversion (all five tensors) ---------
// 8-elem units: hs 1310720 | qw 6553600 | kw 655360 | vw 655360 | ow 6553600
__global__ __launch_bounds__(256) void cvt_all(
    const float* __restrict__ hs, const float* __restrict__ qw,
    const float* __restrict__ kw, const float* __restrict__ vw,
    const float* __restrict__ ow, unsigned short* __restrict__ wsd) {
  long i8 = (long)blockIdx.x * 256 + threadIdx.x;
  const float* src;
  unsigned short* dst;
  long so;
  if (i8 < 1310720)      { src = hs; so = i8;           dst = wsd; }
  else if (i8 < 7864320) { src = qw; so = i8 - 1310720; dst = wsd + 10485760; }
  else if (i8 < 8519680) { src = kw; so = i8 - 7864320; dst = wsd + 62914560; }
  else if (i8 < 9175040) { src = vw; so = i8 - 8519680; dst = wsd + 68157440; }
  else                   { src = ow; so = i8 - 9175040; dst = wsd + 73400320; }
  long e = so * 8;
  float4 a = *reinterpret_cast<const float4*>(src + e);
  float4 b = *reinterpret_cast<const float4*>(src + e + 4);
  union { unsigned short u[8]; uint4 v; } r;
  r.u[0] = f2bf(a.x); r.u[1] = f2bf(a.y); r.u[2] = f2bf(a.z); r.u[3] = f2bf(a.w);
  r.u[4] = f2bf(b.x); r.u[5] = f2bf(b.y); r.u[6] = f2bf(b.z); r.u[7] = f2bf(b.w);
  *reinterpret_cast<uint4*>(dst + e) = r.v;
}

__global__ __launch_bounds__(256) void concat_bias(
    const float* __restrict__ qb, const float* __restrict__ kb,
    const float* __restrict__ vb, float* __restrict__ out) {
  int i = blockIdx.x * 256 + threadIdx.x;
  if (i >= NQKV) return;
  float v;
  if (i < KOFF) v = qb[i];
  else if (i < VOFF) v = kb[i - KOFF];
  else v = vb[i - VOFF];
  out[i] = v;
}

// ---------------- GEMM: 128x128 tile, BK=32 DOUBLE-BUFFERED ----------------
// T3 stage-early/drain-late with residency preserved: As/Bs = 2 x 8 KB each,
// 32 KB total (same as r12's single-buf BK=64 -> 3 blocks/CU). Tile stored as
// 64 LDS-rows x 128 B (2 real rows packed per LDS row, pure linear), swizzle
// byte o -> o ^ (((o>>7)&7)<<4): read mask is lane-constant ((lr>>1)&7)<<4,
// full-wave access is a uniform 2x per bank-quad = the b128 floor. Staging
// source carries the inverse image (rule #21). Per tile: STAGE(next->other),
// 8 ds_read + 16 MFMA, vmcnt(0) hidden under compute, ONE barrier.
template <int OUT_BF16, int HAS_BIAS>
__global__ __launch_bounds__(256, 2) void gemm_db32(
    const unsigned short* __restrict__ A, const unsigned short* __restrict__ W,
    const float* __restrict__ bias, void* __restrict__ Cout,
    int M, int N, int K) {
  __shared__ unsigned short As[2][128 * 32];   // 8 KB each
  __shared__ unsigned short Bs[2][128 * 32];
  const int t = threadIdx.x;
  const int lane = t & 63, wave = t >> 6;
  const int m0 = blockIdx.y * 128, n0 = blockIdx.x * 128;
  const int wr = (wave >> 1) * 64, wc = (wave & 1) * 64;
  const int lr = lane & 15, lg = lane >> 4;
  // staging geometry: 2 chunks/matrix; dest byte o -> logical (row, col)
  int st_row[2], st_col[2];
#pragma unroll
  for (int ch = 0; ch < 2; ++ch) {
    int o = ch * 4096 + wave * 1024 + lane * 16;
    int u = o ^ (((o >> 7) & 7) << 4);         // involution
    st_row[ch] = u >> 6;                        // real row 0..127
    st_col[ch] = u & 63;                        // byte within 64-B row
  }
  f32x4 acc[4][4] = {};
  const int swzl = ((lr >> 1) & 7) << 4;        // lane-constant read mask
  auto STAGE = [&](int buf, int k0) {
#pragma unroll
    for (int ch = 0; ch < 2; ++ch) {
      int od = ch * 4096 + wave * 1024;
      gload_lds16((const char*)A +
                      ((size_t)(m0 + st_row[ch]) * K + k0) * 2 + st_col[ch],
                  (char*)&As[buf][0] + od);
      gload_lds16((const char*)W +
                      ((size_t)(n0 + st_row[ch]) * K + k0) * 2 + st_col[ch],
                  (char*)&Bs[buf][0] + od);
    }
  };
  auto COMPUTE = [&](int buf) {
    bf16x8 af[4], bfr[4];
#pragma unroll
    for (int m = 0; m < 4; ++m) {
      int o = (wr + m * 16 + lr) * 64 + lg * 16;
      af[m] = ld_vec<bf16x8>((const char*)&As[buf][0] + (o ^ swzl));
    }
#pragma unroll
    for (int n = 0; n < 4; ++n) {
      int o = (wc + n * 16 + lr) * 64 + lg * 16;
      bfr[n] = ld_vec<bf16x8>((const char*)&Bs[buf][0] + (o ^ swzl));
    }
#pragma unroll
    for (int m = 0; m < 4; ++m)
#pragma unroll
      for (int n = 0; n < 4; ++n)
        acc[m][n] = __builtin_amdgcn_mfma_f32_16x16x32_bf16(af[m], bfr[n],
                                                            acc[m][n], 0, 0, 0);
  };
  auto FENCE = [&]() {
    asm volatile("s_waitcnt vmcnt(0)" ::: "memory");
    __builtin_amdgcn_s_barrier();
    __builtin_amdgcn_sched_barrier(0);
  };

  STAGE(0, 0);
  __syncthreads();
  for (int k0 = 0; k0 < K; k0 += 64) {          // two BK=32 tiles per iter
    STAGE(1, k0 + 32);
    COMPUTE(0);
    FENCE();
    if (k0 + 64 < K) STAGE(0, k0 + 64);
    COMPUTE(1);
    FENCE();
  }
#pragma unroll
  for (int n = 0; n < 4; ++n) {
    int col = n0 + wc + n * 16 + lr;
    float bv = HAS_BIAS ? bias[col] : 0.0f;
#pragma unroll
    for (int m = 0; m < 4; ++m) {
#pragma unroll
      for (int r = 0; r < 4; ++r) {
        int row = m0 + wr + m * 16 + lg * 4 + r;
        float v = acc[m][n][r] + bv;
        if (OUT_BF16)
          ((unsigned short*)Cout)[(size_t)row * N + col] = f2bf(v);
        else
          ((float*)Cout)[(size_t)row * N + col] = v;
      }
    }
  }
}

// ---------------- RoPE in-place on q,k columns of qkv ----------------
__global__ __launch_bounds__(256) void rope_kernel(
    unsigned short* __restrict__ qkv, const float* __restrict__ cs,
    const float* __restrict__ sn) {
  int idx = blockIdx.x * 256 + threadIdx.x;  // MROWS * 88 * 16 total
  int quad = idx & 15;
  int rest = idx >> 4;
  int slot = rest % 88;
  int row = rest / 88;
  if (row >= MROWS) return;
  int col = slot < NH ? slot * HD : KOFF + (slot - NH) * HD;
  unsigned short* p = qkv + (size_t)row * NQKV + col;
  const float* cp = cs + (size_t)row * HD;
  const float* sp = sn + (size_t)row * HD;
  int d0 = quad * 4;
  float4 c1 = *reinterpret_cast<const float4*>(cp + d0);
  float4 s1 = *reinterpret_cast<const float4*>(sp + d0);
  float4 c2 = *reinterpret_cast<const float4*>(cp + d0 + 64);
  float4 s2 = *reinterpret_cast<const float4*>(sp + d0 + 64);
  ushort4 x1 = *reinterpret_cast<const ushort4*>(p + d0);
  ushort4 x2 = *reinterpret_cast<const ushort4*>(p + d0 + 64);
  ushort4 o1, o2;
  float a, b;
  a = bf2f(x1.x); b = bf2f(x2.x);
  o1.x = f2bf(a * c1.x - b * s1.x); o2.x = f2bf(b * c2.x + a * s2.x);
  a = bf2f(x1.y); b = bf2f(x2.y);
  o1.y = f2bf(a * c1.y - b * s1.y); o2.y = f2bf(b * c2.y + a * s2.y);
  a = bf2f(x1.z); b = bf2f(x2.z);
  o1.z = f2bf(a * c1.z - b * s1.z); o2.z = f2bf(b * c2.z + a * s2.z);
  a = bf2f(x1.w); b = bf2f(x2.w);
  o1.w = f2bf(a * c1.w - b * s1.w); o2.w = f2bf(b * c2.w + a * s2.w);
  *reinterpret_cast<ushort4*>(p + d0) = o1;
  *reinterpret_cast<ushort4*>(p + d0 + 64) = o2;
}

// ---------------- causal GQA flash attention (r8 winning form) ----------
__global__ __launch_bounds__(256, 2) void attn_kernel(
    const unsigned short* __restrict__ qkv, unsigned short* __restrict__ out) {
  __shared__ unsigned short Ks[64][128];     // K tile, swizzled storage
  __shared__ unsigned short Vt[128][64];     // transposed V, group-swizzled
  __shared__ unsigned short Ps[4][32][72];   // per-wave P tile, +8 pad
  const int t = threadIdx.x, lane = t & 63, wave = t >> 6;
  const int lr = lane & 15, lg = lane >> 4;
  const int blk = blockIdx.x;
  const int qt = 7 - blk / 160;              // longest blocks dispatch first
  const int bh = blk % 160;
  const int h = bh % NH, b = bh / NH;
  const int kvh = h / GROUPS;
  const int q0 = qt * 128;
  const int wrow0 = q0 + wave * 32;
  const unsigned short* Qb = qkv + (size_t)(b * SEQ) * NQKV + h * HD;
  const unsigned short* Kb = qkv + (size_t)(b * SEQ) * NQKV + KOFF + kvh * HD;
  const unsigned short* Vb = qkv + (size_t)(b * SEQ) * NQKV + VOFF + kvh * HD;
  int kst_row[4], kst_col[4];
#pragma unroll
  for (int ch = 0; ch < 4; ++ch) {
    int ol = wave * 1024 + ch * 4096 + lane * 16;
    int row = ol >> 8, cbyte = ol & 255;
    kst_row[ch] = row;
    kst_col[ch] = cbyte ^ ((row & 7) << 4);
  }
  bf16x8 qf[2][4];
#pragma unroll
  for (int rb = 0; rb < 2; ++rb)
#pragma unroll
    for (int kk = 0; kk < 4; ++kk)
      qf[rb][kk] = ld_vec<bf16x8>(Qb + (size_t)(wrow0 + rb * 16 + lr) * NQKV +
                                  kk * 32 + lg * 8);
  f32x4 acc[2][8] = {};
  float mrow[2][4], lrow[2][4];
#pragma unroll
  for (int rb = 0; rb < 2; ++rb)
#pragma unroll
    for (int r = 0; r < 4; ++r) { mrow[rb][r] = -__builtin_inff(); lrow[rb][r] = 0.f; }

  const int ntile = (q0 + 128) >> 6;
  for (int tt = 0; tt < ntile; ++tt) {
    const int kv0 = tt * 64;
    __syncthreads();
#pragma unroll
    for (int ch = 0; ch < 4; ++ch) {
      int od = wave * 1024 + ch * 4096;
      gload_lds16((const char*)Kb + ((size_t)(kv0 + kst_row[ch]) * NQKV) * 2 +
                      kst_col[ch],
                  (char*)&Ks[0][0] + od);
    }
#pragma unroll
    for (int i = 0; i < 4; ++i) {
      int e = i * 2048 + t * 8;
      int row = e >> 7, colc = e & 127;
      uint4 dv = ld_vec<uint4>(Vb + (size_t)(kv0 + row) * NQKV + colc);
      const unsigned short* pv = reinterpret_cast<const unsigned short*>(&dv);
#pragma unroll
      for (int j = 0; j < 8; ++j) {
        int dd = colc + j;
        int gp = ((row >> 3) + dd + (dd >> 3)) & 7;
        Vt[dd][(gp << 3) | (row & 7)] = pv[j];
      }
    }
    __syncthreads();
    if (kv0 > wrow0 + 31) continue;
    const bool needMask = (kv0 + 63) > wrow0;
#pragma unroll
    for (int rb = 0; rb < 2; ++rb) {
      f32x4 sf[4] = {};
#pragma unroll
      for (int kk = 0; kk < 4; ++kk) {
#pragma unroll
        for (int cb = 0; cb < 4; ++cb) {
          bf16x8 kfr = ld_vec<bf16x8>(
              (const char*)&Ks[0][0] + (cb * 16 + lr) * 256 +
              ((kk * 64 + lg * 16) ^ ((lr & 7) << 4)));
          sf[cb] = __builtin_amdgcn_mfma_f32_16x16x32_bf16(qf[rb][kk], kfr,
                                                           sf[cb], 0, 0, 0);
        }
      }
#pragma unroll
      for (int r = 0; r < 4; ++r) {
        int qrow = wrow0 + rb * 16 + lg * 4 + r;
        float mx = -3.0e38f;
#pragma unroll
        for (int cb = 0; cb < 4; ++cb) {
          float s = sf[cb][r] * ATTN_SCALE;
          if (needMask && (kv0 + cb * 16 + lr) > qrow) s = -__builtin_inff();
          sf[cb][r] = s;
          mx = fmaxf(mx, s);
        }
        mx = fmaxf(mx, __shfl_xor(mx, 1));
        mx = fmaxf(mx, __shfl_xor(mx, 2));
        mx = fmaxf(mx, __shfl_xor(mx, 4));
        mx = fmaxf(mx, __shfl_xor(mx, 8));
        float mold = mrow[rb][r];
        float mnew = fmaxf(mold, mx);
        float sfac = __expf(mold - mnew);
        mrow[rb][r] = mnew;
        float ps = 0.f;
#pragma unroll
        for (int cb = 0; cb < 4; ++cb) {
          float p = __expf(sf[cb][r] - mnew);
          ps += p;
          Ps[wave][rb * 16 + lg * 4 + r][cb * 16 + lr] = f2bf(p);
        }
        ps += __shfl_xor(ps, 1);
        ps += __shfl_xor(ps, 2);
        ps += __shfl_xor(ps, 4);
        ps += __shfl_xor(ps, 8);
        lrow[rb][r] = lrow[rb][r] * sfac + ps;
#pragma unroll
        for (int n = 0; n < 8; ++n) acc[rb][n][r] *= sfac;
      }
    }
#pragma unroll
    for (int kk = 0; kk < 2; ++kk) {
      bf16x8 vf[8];
#pragma unroll
      for (int cb = 0; cb < 8; ++cb) {
        int dd = cb * 16 + lr;
        int gp = (kk * 4 + lg + dd + (dd >> 3)) & 7;
        vf[cb] = ld_vec<bf16x8>(&Vt[dd][gp << 3]);
      }
#pragma unroll
      for (int rb = 0; rb < 2; ++rb) {
        bf16x8 pa = ld_vec<bf16x8>(&Ps[wave][rb * 16 + lr][kk * 32 + lg * 8]);
#pragma unroll
        for (int cb = 0; cb < 8; ++cb)
          acc[rb][cb] = __builtin_amdgcn_mfma_f32_16x16x32_bf16(pa, vf[cb],
                                                                acc[rb][cb], 0, 0, 0);
      }
    }
  }
#pragma unroll
  for (int rb = 0; rb < 2; ++rb)
#pragma unroll
    for (int n = 0; n < 8; ++n)
#pragma unroll
      for (int r = 0; r < 4; ++r) {
        int qrow = wrow0 + rb * 16 + lg * 4 + r;
        float v = acc[rb][n][r] / lrow[rb][r];
        out[(size_t)(b * SEQ + qrow) * QCOLS + h * HD + n * 16 + lr] = f2bf(v);
      }
}

// ---------------- launch ----------------
extern "C" void kernel_launch(void* const* d_in, const int* in_sizes, int n_in,
                              void* d_out, int out_size, void* d_ws,
                              size_t ws_size, hipStream_t stream) {
  const float* hs   = (const float*)d_in[0];
  const float* cosb = (const float*)d_in[1];
  const float* sinb = (const float*)d_in[2];
  const float* q_w  = (const float*)d_in[3];
  const float* q_b  = (const float*)d_in[4];
  const float* k_w  = (const float*)d_in[5];
  const float* k_b  = (const float*)d_in[6];
  const float* v_w  = (const float*)d_in[7];
  const float* v_b  = (const float*)d_in[8];
  const float* o_w  = (const float*)d_in[9];

  char* ws = (char*)d_ws;
  unsigned short* hsB  = (unsigned short*)(ws);                  // 2048x5120
  unsigned short* wqkv = (unsigned short*)(ws + 20971520ll);     // 12288x5120
  unsigned short* wo   = (unsigned short*)(ws + 146800640ll);    // 5120x10240
  unsigned short* qkv  = (unsigned short*)(ws + 251658240ll);    // 2048x12288
  unsigned short* attn = (unsigned short*)(ws + 301989888ll);    // 2048x10240
  float* bqkv          = (float*)(ws + 343932928ll);             // 12288

  cvt_all<<<dim3(61440), dim3(256), 0, stream>>>(hs, q_w, k_w, v_w, o_w,
                                                 (unsigned short*)ws);
  concat_bias<<<dim3(48), dim3(256), 0, stream>>>(q_b, k_b, v_b, bqkv);

  gemm_db32<1, 1><<<dim3(96, 16), dim3(256), 0, stream>>>(
      hsB, wqkv, bqkv, qkv, MROWS, NQKV, DMODEL);
  rope_kernel<<<dim3(11264), dim3(256), 0, stream>>>(qkv, cosb, sinb);
  attn_kernel<<<dim3(1280), dim3(256), 0, stream>>>(qkv, attn);
  gemm_db32<0, 0><<<dim3(40, 16), dim3(256), 0, stream>>>(
      attn, wo, nullptr, d_out, MROWS, 5120, 10240);
}

// Round 14
// 792.091 us; speedup vs baseline: 1.1713x; 1.1713x over previous
//
#include <hip/hip_runtime.h>
#include <hip/hip_bf16.h>

#define NH 80
#define NKV 8
#define HD 128
#define GROUPS 10
#define SEQ 1024
#define BATCH 2
#define DMODEL 5120
#define NQKV 12288   // 10240 q + 1024 k + 1024 v
#define MROWS 2048   // B*S
#define QCOLS 10240
#define KOFF 10240
#define VOFF 11264
#define ATTN_SCALE 0.08838834764831845f  // 128^-0.5

typedef __attribute__((ext_vector_type(8))) __bf16 bf16x8;
typedef __attribute__((ext_vector_type(4))) float f32x4;

__device__ inline unsigned short f2bf(float f) {
  unsigned u = __float_as_uint(f);
  u = (u + 0x7fffu + ((u >> 16) & 1u)) >> 16;
  return (unsigned short)u;
}
__device__ inline float bf2f(unsigned short h) {
  return __uint_as_float(((unsigned)h) << 16);
}

template <typename T>
__device__ inline T ld_vec(const void* p) {
  T v;
  __builtin_memcpy(&v, p, sizeof(T));
  return v;
}

__device__ inline void gload_lds16(const void* g, void* l) {
  __builtin_amdgcn_global_load_lds(
      (const __attribute__((address_space(1))) void*)g,
      (__attribute__((address_space(3))) void*)l, 16, 0, 0);
}

// ---------------- fused fp32 -> bf16 conversion (all five tensors) ---------
// 8-elem units: hs 1310720 | qw 6553600 | kw 655360 | vw 655360 | ow 6553600
// cumulative:   1310720 / 7864320 / 8519680 / 9175040 / 15728640  (exact grid)
__global__ __launch_bounds__(256) void cvt_all(
    const float* __restrict__ hs, const float* __restrict__ qw,
    const float* __restrict__ kw, const float* __restrict__ vw,
    const float* __restrict__ ow, unsigned short* __restrict__ wsd) {
  long i8 = (long)blockIdx.x * 256 + threadIdx.x;
  const float* src;
  unsigned short* dst;
  long so;
  if (i8 < 1310720)      { src = hs; so = i8;           dst = wsd; }
  else if (i8 < 7864320) { src = qw; so = i8 - 1310720; dst = wsd + 10485760; }
  else if (i8 < 8519680) { src = kw; so = i8 - 7864320; dst = wsd + 62914560; }
  else if (i8 < 9175040) { src = vw; so = i8 - 8519680; dst = wsd + 68157440; }
  else                   { src = ow; so = i8 - 9175040; dst = wsd + 73400320; }
  long e = so * 8;
  float4 a = *reinterpret_cast<const float4*>(src + e);
  float4 b = *reinterpret_cast<const float4*>(src + e + 4);
  union { unsigned short u[8]; uint4 v; } r;
  r.u[0] = f2bf(a.x); r.u[1] = f2bf(a.y); r.u[2] = f2bf(a.z); r.u[3] = f2bf(a.w);
  r.u[4] = f2bf(b.x); r.u[5] = f2bf(b.y); r.u[6] = f2bf(b.z); r.u[7] = f2bf(b.w);
  *reinterpret_cast<uint4*>(dst + e) = r.v;
}

__global__ __launch_bounds__(256) void concat_bias(
    const float* __restrict__ qb, const float* __restrict__ kb,
    const float* __restrict__ vb, float* __restrict__ out) {
  int i = blockIdx.x * 256 + threadIdx.x;
  if (i >= NQKV) return;
  float v;
  if (i < KOFF) v = qb[i];
  else if (i < VOFF) v = kb[i - KOFF];
  else v = vb[i - VOFF];
  out[i] = v;
}

// ---------------- GEMM (both projections, r9/r12 proven): 128x128, BK=64 ----
// 4 waves 2x2, per-wave 64x64, bank swizzle col^=((row&7)<<4) both-sides.
// Empirical optimum of this session: wider per-wave outputs (r10/r11) lose
// residency; all pipelining grafts (r2-r4 8-phase, r6/r13 dbuf) regressed.
template <int OUT_BF16, int HAS_BIAS>
__global__ __launch_bounds__(256, 4) void gemm_bt64(
    const unsigned short* __restrict__ A, const unsigned short* __restrict__ W,
    const float* __restrict__ bias, void* __restrict__ Cout,
    int M, int N, int K) {
  __shared__ unsigned short As[128 * 64];   // 16 KB, rows of 128 B
  __shared__ unsigned short Bs[128 * 64];
  const int t = threadIdx.x;
  const int lane = t & 63, wave = t >> 6;
  const int m0 = blockIdx.y * 128, n0 = blockIdx.x * 128;
  const int wr = (wave >> 1) * 64, wc = (wave & 1) * 64;
  const int lr = lane & 15, lg = lane >> 4;
  int st_row[4], st_col[4];
#pragma unroll
  for (int ch = 0; ch < 4; ++ch) {
    int ol = wave * 1024 + ch * 4096 + lane * 16;
    int row = ol >> 7, cb = ol & 127;
    st_row[ch] = row;
    st_col[ch] = cb ^ ((row & 7) << 4);
  }
  f32x4 acc[4][4] = {};
  const int swz = (lr & 7) << 4;
  for (int k0 = 0; k0 < K; k0 += 64) {
#pragma unroll
    for (int ch = 0; ch < 4; ++ch) {
      int od = wave * 1024 + ch * 4096;
      gload_lds16((const char*)A +
                      ((size_t)(m0 + st_row[ch]) * K + k0) * 2 + st_col[ch],
                  (char*)As + od);
      gload_lds16((const char*)W +
                      ((size_t)(n0 + st_row[ch]) * K + k0) * 2 + st_col[ch],
                  (char*)Bs + od);
    }
    __syncthreads();
    bf16x8 af[4][2], bfr[4][2];
#pragma unroll
    for (int ks = 0; ks < 2; ++ks) {
      int colb = (ks * 64 + lg * 16) ^ swz;
#pragma unroll
      for (int m = 0; m < 4; ++m)
        af[m][ks] =
            ld_vec<bf16x8>((const char*)As + (wr + m * 16 + lr) * 128 + colb);
#pragma unroll
      for (int n = 0; n < 4; ++n)
        bfr[n][ks] =
            ld_vec<bf16x8>((const char*)Bs + (wc + n * 16 + lr) * 128 + colb);
    }
#pragma unroll
    for (int ks = 0; ks < 2; ++ks)
#pragma unroll
      for (int m = 0; m < 4; ++m)
#pragma unroll
        for (int n = 0; n < 4; ++n)
          acc[m][n] = __builtin_amdgcn_mfma_f32_16x16x32_bf16(
              af[m][ks], bfr[n][ks], acc[m][n], 0, 0, 0);
    __syncthreads();
  }
#pragma unroll
  for (int n = 0; n < 4; ++n) {
    int col = n0 + wc + n * 16 + lr;
    float bv = HAS_BIAS ? bias[col] : 0.0f;
#pragma unroll
    for (int m = 0; m < 4; ++m) {
#pragma unroll
      for (int r = 0; r < 4; ++r) {
        int row = m0 + wr + m * 16 + lg * 4 + r;
        float v = acc[m][n][r] + bv;
        if (OUT_BF16)
          ((unsigned short*)Cout)[(size_t)row * N + col] = f2bf(v);
        else
          ((float*)Cout)[(size_t)row * N + col] = v;
      }
    }
  }
}

// ---------------- RoPE in-place on q,k columns of qkv ----------------
__global__ __launch_bounds__(256) void rope_kernel(
    unsigned short* __restrict__ qkv, const float* __restrict__ cs,
    const float* __restrict__ sn) {
  int idx = blockIdx.x * 256 + threadIdx.x;  // MROWS * 88 * 16 total
  int quad = idx & 15;
  int rest = idx >> 4;
  int slot = rest % 88;
  int row = rest / 88;
  if (row >= MROWS) return;
  int col = slot < NH ? slot * HD : KOFF + (slot - NH) * HD;
  unsigned short* p = qkv + (size_t)row * NQKV + col;
  const float* cp = cs + (size_t)row * HD;
  const float* sp = sn + (size_t)row * HD;
  int d0 = quad * 4;
  float4 c1 = *reinterpret_cast<const float4*>(cp + d0);
  float4 s1 = *reinterpret_cast<const float4*>(sp + d0);
  float4 c2 = *reinterpret_cast<const float4*>(cp + d0 + 64);
  float4 s2 = *reinterpret_cast<const float4*>(sp + d0 + 64);
  ushort4 x1 = *reinterpret_cast<const ushort4*>(p + d0);
  ushort4 x2 = *reinterpret_cast<const ushort4*>(p + d0 + 64);
  ushort4 o1, o2;
  float a, b;
  a = bf2f(x1.x); b = bf2f(x2.x);
  o1.x = f2bf(a * c1.x - b * s1.x); o2.x = f2bf(b * c2.x + a * s2.x);
  a = bf2f(x1.y); b = bf2f(x2.y);
  o1.y = f2bf(a * c1.y - b * s1.y); o2.y = f2bf(b * c2.y + a * s2.y);
  a = bf2f(x1.z); b = bf2f(x2.z);
  o1.z = f2bf(a * c1.z - b * s1.z); o2.z = f2bf(b * c2.z + a * s2.z);
  a = bf2f(x1.w); b = bf2f(x2.w);
  o1.w = f2bf(a * c1.w - b * s1.w); o2.w = f2bf(b * c2.w + a * s2.w);
  *reinterpret_cast<ushort4*>(p + d0) = o1;
  *reinterpret_cast<ushort4*>(p + d0 + 64) = o2;
}

// ---------------- causal GQA flash attention (r8 winning form) ----------
__global__ __launch_bounds__(256, 2) void attn_kernel(
    const unsigned short* __restrict__ qkv, unsigned short* __restrict__ out) {
  __shared__ unsigned short Ks[64][128];     // K tile, swizzled storage
  __shared__ unsigned short Vt[128][64];     // transposed V, group-swizzled
  __shared__ unsigned short Ps[4][32][72];   // per-wave P tile, +8 pad
  const int t = threadIdx.x, lane = t & 63, wave = t >> 6;
  const int lr = lane & 15, lg = lane >> 4;
  const int blk = blockIdx.x;
  const int qt = 7 - blk / 160;              // longest blocks dispatch first
  const int bh = blk % 160;
  const int h = bh % NH, b = bh / NH;
  const int kvh = h / GROUPS;
  const int q0 = qt * 128;
  const int wrow0 = q0 + wave * 32;
  const unsigned short* Qb = qkv + (size_t)(b * SEQ) * NQKV + h * HD;
  const unsigned short* Kb = qkv + (size_t)(b * SEQ) * NQKV + KOFF + kvh * HD;
  const unsigned short* Vb = qkv + (size_t)(b * SEQ) * NQKV + VOFF + kvh * HD;
  int kst_row[4], kst_col[4];
#pragma unroll
  for (int ch = 0; ch < 4; ++ch) {
    int ol = wave * 1024 + ch * 4096 + lane * 16;
    int row = ol >> 8, cbyte = ol & 255;
    kst_row[ch] = row;
    kst_col[ch] = cbyte ^ ((row & 7) << 4);
  }
  bf16x8 qf[2][4];
#pragma unroll
  for (int rb = 0; rb < 2; ++rb)
#pragma unroll
    for (int kk = 0; kk < 4; ++kk)
      qf[rb][kk] = ld_vec<bf16x8>(Qb + (size_t)(wrow0 + rb * 16 + lr) * NQKV +
                                  kk * 32 + lg * 8);
  f32x4 acc[2][8] = {};
  float mrow[2][4], lrow[2][4];
#pragma unroll
  for (int rb = 0; rb < 2; ++rb)
#pragma unroll
    for (int r = 0; r < 4; ++r) { mrow[rb][r] = -__builtin_inff(); lrow[rb][r] = 0.f; }

  const int ntile = (q0 + 128) >> 6;
  for (int tt = 0; tt < ntile; ++tt) {
    const int kv0 = tt * 64;
    __syncthreads();
#pragma unroll
    for (int ch = 0; ch < 4; ++ch) {
      int od = wave * 1024 + ch * 4096;
      gload_lds16((const char*)Kb + ((size_t)(kv0 + kst_row[ch]) * NQKV) * 2 +
                      kst_col[ch],
                  (char*)&Ks[0][0] + od);
    }
#pragma unroll
    for (int i = 0; i < 4; ++i) {
      int e = i * 2048 + t * 8;
      int row = e >> 7, colc = e & 127;
      uint4 dv = ld_vec<uint4>(Vb + (size_t)(kv0 + row) * NQKV + colc);
      const unsigned short* pv = reinterpret_cast<const unsigned short*>(&dv);
#pragma unroll
      for (int j = 0; j < 8; ++j) {
        int dd = colc + j;
        int gp = ((row >> 3) + dd + (dd >> 3)) & 7;
        Vt[dd][(gp << 3) | (row & 7)] = pv[j];
      }
    }
    __syncthreads();
    if (kv0 > wrow0 + 31) continue;
    const bool needMask = (kv0 + 63) > wrow0;
#pragma unroll
    for (int rb = 0; rb < 2; ++rb) {
      f32x4 sf[4] = {};
#pragma unroll
      for (int kk = 0; kk < 4; ++kk) {
#pragma unroll
        for (int cb = 0; cb < 4; ++cb) {
          bf16x8 kfr = ld_vec<bf16x8>(
              (const char*)&Ks[0][0] + (cb * 16 + lr) * 256 +
              ((kk * 64 + lg * 16) ^ ((lr & 7) << 4)));
          sf[cb] = __builtin_amdgcn_mfma_f32_16x16x32_bf16(qf[rb][kk], kfr,
                                                           sf[cb], 0, 0, 0);
        }
      }
#pragma unroll
      for (int r = 0; r < 4; ++r) {
        int qrow = wrow0 + rb * 16 + lg * 4 + r;
        float mx = -3.0e38f;
#pragma unroll
        for (int cb = 0; cb < 4; ++cb) {
          float s = sf[cb][r] * ATTN_SCALE;
          if (needMask && (kv0 + cb * 16 + lr) > qrow) s = -__builtin_inff();
          sf[cb][r] = s;
          mx = fmaxf(mx, s);
        }
        mx = fmaxf(mx, __shfl_xor(mx, 1));
        mx = fmaxf(mx, __shfl_xor(mx, 2));
        mx = fmaxf(mx, __shfl_xor(mx, 4));
        mx = fmaxf(mx, __shfl_xor(mx, 8));
        float mold = mrow[rb][r];
        float mnew = fmaxf(mold, mx);
        float sfac = __expf(mold - mnew);
        mrow[rb][r] = mnew;
        float ps = 0.f;
#pragma unroll
        for (int cb = 0; cb < 4; ++cb) {
          float p = __expf(sf[cb][r] - mnew);
          ps += p;
          Ps[wave][rb * 16 + lg * 4 + r][cb * 16 + lr] = f2bf(p);
        }
        ps += __shfl_xor(ps, 1);
        ps += __shfl_xor(ps, 2);
        ps += __shfl_xor(ps, 4);
        ps += __shfl_xor(ps, 8);
        lrow[rb][r] = lrow[rb][r] * sfac + ps;
#pragma unroll
        for (int n = 0; n < 8; ++n) acc[rb][n][r] *= sfac;
      }
    }
#pragma unroll
    for (int kk = 0; kk < 2; ++kk) {
      bf16x8 vf[8];
#pragma unroll
      for (int cb = 0; cb < 8; ++cb) {
        int dd = cb * 16 + lr;
        int gp = (kk * 4 + lg + dd + (dd >> 3)) & 7;
        vf[cb] = ld_vec<bf16x8>(&Vt[dd][gp << 3]);
      }
#pragma unroll
      for (int rb = 0; rb < 2; ++rb) {
        bf16x8 pa = ld_vec<bf16x8>(&Ps[wave][rb * 16 + lr][kk * 32 + lg * 8]);
#pragma unroll
        for (int cb = 0; cb < 8; ++cb)
          acc[rb][cb] = __builtin_amdgcn_mfma_f32_16x16x32_bf16(pa, vf[cb],
                                                                acc[rb][cb], 0, 0, 0);
      }
    }
  }
#pragma unroll
  for (int rb = 0; rb < 2; ++rb)
#pragma unroll
    for (int n = 0; n < 8; ++n)
#pragma unroll
      for (int r = 0; r < 4; ++r) {
        int qrow = wrow0 + rb * 16 + lg * 4 + r;
        float v = acc[rb][n][r] / lrow[rb][r];
        out[(size_t)(b * SEQ + qrow) * QCOLS + h * HD + n * 16 + lr] = f2bf(v);
      }
}

// ---------------- launch ----------------
extern "C" void kernel_launch(void* const* d_in, const int* in_sizes, int n_in,
                              void* d_out, int out_size, void* d_ws,
                              size_t ws_size, hipStream_t stream) {
  const float* hs   = (const float*)d_in[0];
  const float* cosb = (const float*)d_in[1];
  const float* sinb = (const float*)d_in[2];
  const float* q_w  = (const float*)d_in[3];
  const float* q_b  = (const float*)d_in[4];
  const float* k_w  = (const float*)d_in[5];
  const float* k_b  = (const float*)d_in[6];
  const float* v_w  = (const float*)d_in[7];
  const float* v_b  = (const float*)d_in[8];
  const float* o_w  = (const float*)d_in[9];

  char* ws = (char*)d_ws;
  unsigned short* hsB  = (unsigned short*)(ws);                  // 2048x5120
  unsigned short* wqkv = (unsigned short*)(ws + 20971520ll);     // 12288x5120
  unsigned short* wo   = (unsigned short*)(ws + 146800640ll);    // 5120x10240
  unsigned short* qkv  = (unsigned short*)(ws + 251658240ll);    // 2048x12288
  unsigned short* attn = (unsigned short*)(ws + 301989888ll);    // 2048x10240
  float* bqkv          = (float*)(ws + 343932928ll);             // 12288

  cvt_all<<<dim3(61440), dim3(256), 0, stream>>>(hs, q_w, k_w, v_w, o_w,
                                                 (unsigned short*)ws);
  concat_bias<<<dim3(48), dim3(256), 0, stream>>>(q_b, k_b, v_b, bqkv);

  gemm_bt64<1, 1><<<dim3(96, 16), dim3(256), 0, stream>>>(
      hsB, wqkv, bqkv, qkv, MROWS, NQKV, DMODEL);
  rope_kernel<<<dim3(11264), dim3(256), 0, stream>>>(qkv, cosb, sinb);
  attn_kernel<<<dim3(1280), dim3(256), 0, stream>>>(qkv, attn);
  gemm_bt64<0, 0><<<dim3(40, 16), dim3(256), 0, stream>>>(
      attn, wo, nullptr, d_out, MROWS, 5120, 10240);
}